// Round 6
// baseline (271.325 us; speedup 1.0000x reference)
//
#include <hip/hip_runtime.h>
#include <hip/hip_fp16.h>
#include <math.h>

// ---------------------------------------------------------------------------
// GAT 2-layer forward. N=50000, E=1.6M (+N self loops), F: 128 -> (4x32) -> 64.
// R2: CSR via two-pass bucket sort of packed (dst<<16|src) codes.
// R4: fp16-MFMA GEMMs with fused attention-dot epilogue; fp16 inter-stage.
// R5: LDS (exp,offset) exchange in aggregates.
// R6: (a) channel-split aggregation - one dispatch, first half of grid does
//     ch [0,D/2) (working set halves; L2 capacity-miss rate drops), second
//     half does [D/2,D); (b) splitA + gemm_attn1 merged into one fat kernel
//     (independent, different pipes); (c) scan folded into passB. 8->6 nodes.
// ---------------------------------------------------------------------------

#define NB_BUCKETS 256   // max coarse buckets (dst>>8); actual used = ceil(N/256)
#define BCAP 16384       // fixed capacity per coarse bucket region (avg ~8448)

typedef _Float16 half8 __attribute__((ext_vector_type(8)));
typedef float    floatx4 __attribute__((ext_vector_type(4)));

__device__ __forceinline__ unsigned short f2h_bits(float f) {
    return __half_as_ushort(__float2half(f));
}
__device__ __forceinline__ float h2f_lo(unsigned int u) {
    return __half2float(__ushort_as_half((unsigned short)(u & 0xFFFFu)));
}
__device__ __forceinline__ float h2f_hi(unsigned int u) {
    return __half2float(__ushort_as_half((unsigned short)(u >> 16)));
}

// ---------------------------------------------------------------------------
// splitA body: block-aggregated split into coarse buckets by dst>>8
// ---------------------------------------------------------------------------
__device__ void splitA_body(int bx, const int* __restrict__ eidx,
        unsigned int* __restrict__ tmp, int* __restrict__ coarse_fill,
        int E, int etot, int nb)
{
    __shared__ int hist[NB_BUCKETS];
    __shared__ int gb[NB_BUCKETS];
    __shared__ int cnt2[NB_BUCKETS];
    int t = threadIdx.x;
    if (t < nb) { hist[t] = 0; cnt2[t] = 0; }
    __syncthreads();

    unsigned int val[16];
    int bkt[16];
    int base = bx * 4096;
    #pragma unroll
    for (int i = 0; i < 16; i++) {
        int idx = base + i * 256 + t;
        if (idx < etot) {
            unsigned int s, d;
            if (idx < E) { s = (unsigned int)eidx[idx]; d = (unsigned int)eidx[E + idx]; }
            else         { s = (unsigned int)(idx - E); d = s; }
            val[i] = (d << 16) | s;
            bkt[i] = (int)(d >> 8);
            atomicAdd(&hist[bkt[i]], 1);
        } else {
            bkt[i] = -1;
        }
    }
    __syncthreads();
    if (t < nb) {
        int n = hist[t];
        gb[t] = (n > 0) ? atomicAdd(&coarse_fill[t], n) : 0;
    }
    __syncthreads();
    #pragma unroll
    for (int i = 0; i < 16; i++) {
        if (bkt[i] >= 0) {
            int loc = atomicAdd(&cnt2[bkt[i]], 1);
            tmp[(size_t)bkt[i] * BCAP + gb[bkt[i]] + loc] = val[i];
        }
    }
}

// ---------------------------------------------------------------------------
// GEMM (fp16 MFMA) + attention dots + fp16 payload emission (device body).
// ---------------------------------------------------------------------------
template<int NT, int H, bool AF16>
__device__ void gemm_attn_body(int bx,
        const void* __restrict__ Xv, const float* __restrict__ W,
        const float* __restrict__ att_s, const float* __restrict__ att_d,
        unsigned short* __restrict__ Hf16, float* __restrict__ as_,
        float* __restrict__ ad_, int M)
{
    constexpr int D = NT * 16;      // output width
    constexpr int C = D / H;        // channels per head
    __shared__ _Float16 Bs[NT * 4 * 64 * 8];

    int t = threadIdx.x;
    for (int idx = t; idx < 128 * D; idx += 256) {
        int k = idx / D;
        int n = idx - k * D;
        int nt = n >> 4, ks = k >> 5;
        int lane = (((k >> 3) & 3) << 4) | (n & 15);
        int j = k & 7;
        Bs[(((nt * 4 + ks) * 64 + lane) << 3) + j] = (_Float16)W[idx];
    }
    __syncthreads();

    int lane = t & 63;
    int wv = t >> 6;
    int quad = lane >> 4, colL = lane & 15;
    int row0 = bx * 64 + wv * 16;

    int arow = row0 + colL; if (arow > M - 1) arow = M - 1;
    half8 afrag[4];
    if constexpr (AF16) {
        const unsigned short* Xh = (const unsigned short*)Xv;
        #pragma unroll
        for (int ks = 0; ks < 4; ks++)
            afrag[ks] = *(const half8*)(const void*)(Xh + (size_t)arow * 128 + ks * 32 + quad * 8);
    } else {
        const float* Xf = (const float*)Xv;
        #pragma unroll
        for (int ks = 0; ks < 4; ks++) {
            const float* pa = Xf + (size_t)arow * 128 + ks * 32 + quad * 8;
            float4 a0 = *(const float4*)pa;
            float4 a1 = *(const float4*)(pa + 4);
            half8 f;
            f[0] = (_Float16)a0.x; f[1] = (_Float16)a0.y;
            f[2] = (_Float16)a0.z; f[3] = (_Float16)a0.w;
            f[4] = (_Float16)a1.x; f[5] = (_Float16)a1.y;
            f[6] = (_Float16)a1.z; f[7] = (_Float16)a1.w;
            afrag[ks] = f;
        }
    }

    floatx4 acc[NT];
    #pragma unroll
    for (int nt = 0; nt < NT; nt++) {
        floatx4 c = {0.f, 0.f, 0.f, 0.f};
        #pragma unroll
        for (int ks = 0; ks < 4; ks++) {
            half8 b = *(half8*)(void*)&Bs[(((nt * 4 + ks) * 64 + lane) << 3)];
            c = __builtin_amdgcn_mfma_f32_16x16x32_f16(afrag[ks], b, c, 0, 0, 0);
        }
        acc[nt] = c;
    }

    float atts[NT], attd[NT];
    #pragma unroll
    for (int nt = 0; nt < NT; nt++) {
        int ch = nt * 16 + colL;
        atts[nt] = att_s[ch];
        attd[nt] = att_d[ch];
    }
    float ps[H][4], pd[H][4];
    #pragma unroll
    for (int h = 0; h < H; h++)
        #pragma unroll
        for (int r = 0; r < 4; r++) { ps[h][r] = 0.f; pd[h][r] = 0.f; }
    #pragma unroll
    for (int nt = 0; nt < NT; nt++) {
        int h = (nt * 16) / C;
        #pragma unroll
        for (int r = 0; r < 4; r++) {
            ps[h][r] += acc[nt][r] * atts[nt];
            pd[h][r] += acc[nt][r] * attd[nt];
        }
    }
    #pragma unroll
    for (int h = 0; h < H; h++)
        #pragma unroll
        for (int r = 0; r < 4; r++)
            #pragma unroll
            for (int off = 1; off < 16; off <<= 1) {
                ps[h][r] += __shfl_xor(ps[h][r], off);
                pd[h][r] += __shfl_xor(pd[h][r], off);
            }
    if (colL < H) {
        #pragma unroll
        for (int r = 0; r < 4; r++) {
            int row = row0 + quad * 4 + r;
            if (row < M) {
                float vs, vd;
                if constexpr (H == 4) {
                    vs = colL == 0 ? ps[0][r] : colL == 1 ? ps[1][r] : colL == 2 ? ps[2][r] : ps[3][r];
                    vd = colL == 0 ? pd[0][r] : colL == 1 ? pd[1][r] : colL == 2 ? pd[2][r] : pd[3][r];
                } else {
                    vs = ps[0][r]; vd = pd[0][r];
                }
                as_[(size_t)row * H + colL] = vs;
                ad_[(size_t)row * H + colL] = vd;
            }
        }
    }

    #pragma unroll
    for (int r = 0; r < 4; r++) {
        int row = row0 + quad * 4 + r;
        if (row < M) {
            #pragma unroll
            for (int nt = 0; nt < NT; nt++)
                Hf16[(size_t)row * D + nt * 16 + colL] = f2h_bits(acc[nt][r]);
        }
    }
}

// ---------------------------------------------------------------------------
// Fat kernel: gemm_attn1 (blocks [0,nbG)) + splitA (blocks [nbG, nbG+nbA)).
// Independent work, different pipes (MFMA vs LDS/mem) -> true overlap.
// ---------------------------------------------------------------------------
__global__ __launch_bounds__(256) void build_and_gemm1_kernel(
        const int* __restrict__ eidx, unsigned int* __restrict__ tmp,
        int* __restrict__ cfill, int E, int etot, int nb,
        const float* __restrict__ x, const float* __restrict__ W1,
        const float* __restrict__ att_s, const float* __restrict__ att_d,
        unsigned short* __restrict__ h1f16, float* __restrict__ as1,
        float* __restrict__ ad1, int M, int nbG)
{
    if ((int)blockIdx.x < nbG)
        gemm_attn_body<8, 4, false>((int)blockIdx.x, x, W1, att_s, att_d,
                                    h1f16, as1, ad1, M);
    else
        splitA_body((int)blockIdx.x - nbG, eidx, tmp, cfill, E, etot, nb);
}

// standalone layer-2 gemm+attn
__global__ __launch_bounds__(256) void gemm_attn2_kernel(
        const void* __restrict__ Xv, const float* __restrict__ W,
        const float* __restrict__ att_s, const float* __restrict__ att_d,
        unsigned short* __restrict__ Hf16, float* __restrict__ as_,
        float* __restrict__ ad_, int M)
{
    gemm_attn_body<4, 1, true>((int)blockIdx.x, Xv, W, att_s, att_d, Hf16, as_, ad_, M);
}

// ---------------------------------------------------------------------------
// pass B with inline scan: per-bucket counting sort by dst&255 -> col + rowp.
// ---------------------------------------------------------------------------
__global__ __launch_bounds__(1024) void passB_kernel(const unsigned int* __restrict__ tmp,
        const int* __restrict__ cfill, int* __restrict__ col,
        int* __restrict__ rowp, int N_, int nb, int etot)
{
    __shared__ int sd[256];
    __shared__ int hist2[256];
    __shared__ int scn[256];
    __shared__ int off2[256];
    int b = blockIdx.x;
    int t = threadIdx.x;

    // inline exclusive scan of cfill[0..nb) (each block redoes it; tiny)
    int cf = 0;
    if (t < 256) { cf = (t < nb) ? cfill[t] : 0; sd[t] = cf; }
    __syncthreads();
    for (int off = 1; off < 256; off <<= 1) {
        int y = 0;
        if (t < 256 && t >= off) y = sd[t - off];
        __syncthreads();
        if (t < 256) sd[t] += y;
        __syncthreads();
    }
    int base = sd[b] - cfill[b];     // exclusive prefix for this bucket
    int n = cfill[b];
    const unsigned int* seg = tmp + (size_t)b * BCAP;

    if (t < 256) hist2[t] = 0;
    __syncthreads();
    for (int i = t; i < n; i += 1024) {
        unsigned int v = seg[i];
        atomicAdd(&hist2[(v >> 16) & 255], 1);
    }
    __syncthreads();
    int myc = (t < 256) ? hist2[t] : 0;
    if (t < 256) scn[t] = myc;
    __syncthreads();
    for (int off = 1; off < 256; off <<= 1) {
        int y = 0;
        if (t < 256 && t >= off) y = scn[t - off];
        __syncthreads();
        if (t < 256) scn[t] += y;
        __syncthreads();
    }
    if (t < 256) {
        int excl = scn[t] - myc;
        off2[t] = excl;
        int node = b * 256 + t;
        if (node <= N_) rowp[node] = base + excl;
        if (node == N_) rowp[N_] = etot;   // also covered by base+excl; keep exact
    }
    __syncthreads();
    for (int i = t; i < n; i += 1024) {
        unsigned int v = seg[i];
        int bin = (v >> 16) & 255;
        int loc = atomicAdd(&off2[bin], 1);
        col[base + loc] = (int)(v & 0xFFFFu);
    }
}

// ---------------------------------------------------------------------------
// Channel-split fused online-softmax aggregate. One dispatch; blocks [0,nbh)
// handle channels [0,D/2), blocks [nbh,2*nbh) channels [D/2,D). Working set
// per temporal half is payload/2 -> lower L2 capacity-miss rate.
// ---------------------------------------------------------------------------
template<int H, int C, bool ELU_, bool OUTF16>
__global__ __launch_bounds__(256) void aggregate_split(
        const int* __restrict__ row_ptr, const int* __restrict__ col_src,
        const unsigned short* __restrict__ payload, const float* __restrict__ asv,
        const float* __restrict__ adv, const float* __restrict__ bias,
        void* __restrict__ outv, int nnodes, int nbh)
{
    constexpr int D = H * C;
    constexpr int HSPAN = D / 2;        // channels per temporal half
    constexpr int CPL = 8;              // channels per lane (uint4 of halves)
    constexpr int LPE = HSPAN / CPL;    // lanes per edge: 8 (L1) or 4 (L2)
    constexpr int EPI = 64 / LPE;       // edges per inner iter: 8 or 16
    __shared__ float2 exs[4][H][65];
    int half = ((int)blockIdx.x >= nbh) ? 1 : 0;
    int nodeblk = (int)blockIdx.x - half * nbh;
    int wave = threadIdx.x >> 6, lane = threadIdx.x & 63;
    int node = nodeblk * 4 + wave;
    if (node >= nnodes) return;
    int ch0 = half * HSPAN;
    int start = row_ptr[node];
    int deg   = row_ptr[node + 1] - start;   // >= 1 (self loop)
    int li  = lane & (LPE - 1);
    int sub = lane / LPE;
    int myh = (ch0 + li * CPL) / C;
    int lane_off = ch0 * 2 + li * 16;        // byte offset within a row

    float adh[H];
    #pragma unroll
    for (int h = 0; h < H; h++) adh[h] = adv[(size_t)node * H + h];

    float m[H];
    #pragma unroll
    for (int h = 0; h < H; h++) m[h] = -3.0e38f;
    float acc[CPL];
    #pragma unroll
    for (int k = 0; k < CPL; k++) acc[k] = 0.f;
    float sacc = 0.f;
    const char* pb = (const char*)payload;

    for (int c0 = 0; c0 < deg; c0 += 64) {
        int cnt = deg - c0; if (cnt > 64) cnt = 64;
        int idx = c0 + lane;
        int svec = 0;
        float e[H];
        if (idx < deg) {
            svec = col_src[start + idx];
            if constexpr (H == 4) {
                float4 av = *(const float4*)(asv + (size_t)svec * 4);
                float t0 = av.x + adh[0], t1 = av.y + adh[1];
                float t2 = av.z + adh[2], t3 = av.w + adh[3];
                e[0] = fmaxf(t0, 0.2f * t0); e[1] = fmaxf(t1, 0.2f * t1);
                e[2] = fmaxf(t2, 0.2f * t2); e[3] = fmaxf(t3, 0.2f * t3);
            } else {
                float tt = asv[svec] + adh[0];
                e[0] = fmaxf(tt, 0.2f * tt);
            }
        } else {
            #pragma unroll
            for (int h = 0; h < H; h++) e[h] = -3.0e38f;
        }
        // chunk max per head -> running max update + rescale
        float nm[H];
        #pragma unroll
        for (int h = 0; h < H; h++) {
            float v = e[h];
            #pragma unroll
            for (int off = 32; off >= 1; off >>= 1)
                v = fmaxf(v, __shfl_xor(v, off));
            nm[h] = fmaxf(m[h], v);
        }
        float sc = __expf(m[myh] - nm[myh]);  // first chunk: 0
        sacc *= sc;
        #pragma unroll
        for (int k = 0; k < CPL; k++) acc[k] *= sc;
        #pragma unroll
        for (int h = 0; h < H; h++) m[h] = nm[h];

        // producer: {exp, row byte-offset} per head into wave-local LDS
        unsigned int boff = (unsigned int)svec * (unsigned int)(D * 2);
        float boff_f = __uint_as_float(boff);
        #pragma unroll
        for (int h = 0; h < H; h++) {
            float ex = (idx < deg) ? __expf(e[h] - m[h]) : 0.f;
            exs[wave][h][lane] = make_float2(ex, boff_f);
        }

        // consumer: EPI edges per iteration, no cross-lane ops, no masking
        int iters = (cnt + EPI - 1) / EPI;
        #pragma unroll 2
        for (int it = 0; it < iters; it++) {
            int el = it * EPI + sub;
            float2 v = exs[wave][myh][el];
            float exj = v.x;
            unsigned int off = __float_as_uint(v.y);
            uint4 hv = *(const uint4*)(const void*)(pb + off + lane_off);
            sacc += exj;
            acc[0] = fmaf(h2f_lo(hv.x), exj, acc[0]);
            acc[1] = fmaf(h2f_hi(hv.x), exj, acc[1]);
            acc[2] = fmaf(h2f_lo(hv.y), exj, acc[2]);
            acc[3] = fmaf(h2f_hi(hv.y), exj, acc[3]);
            acc[4] = fmaf(h2f_lo(hv.z), exj, acc[4]);
            acc[5] = fmaf(h2f_hi(hv.z), exj, acc[5]);
            acc[6] = fmaf(h2f_lo(hv.w), exj, acc[6]);
            acc[7] = fmaf(h2f_hi(hv.w), exj, acc[7]);
        }
    }

    #pragma unroll
    for (int off = LPE; off < 64; off <<= 1) {
        sacc += __shfl_xor(sacc, off);
        #pragma unroll
        for (int k = 0; k < CPL; k++) acc[k] += __shfl_xor(acc[k], off);
    }
    if (sub == 0) {
        float inv = 1.f / (sacc + 1e-16f);
        int ch = ch0 + li * CPL;
        float r[CPL];
        #pragma unroll
        for (int k = 0; k < CPL; k++) {
            r[k] = acc[k] * inv + bias[ch + k];
            if (ELU_) r[k] = r[k] > 0.f ? r[k] : (__expf(r[k]) - 1.f);
        }
        if constexpr (OUTF16) {
            unsigned short* o = (unsigned short*)outv;
            unsigned int w0 = (unsigned int)f2h_bits(r[0]) | ((unsigned int)f2h_bits(r[1]) << 16);
            unsigned int w1 = (unsigned int)f2h_bits(r[2]) | ((unsigned int)f2h_bits(r[3]) << 16);
            unsigned int w2 = (unsigned int)f2h_bits(r[4]) | ((unsigned int)f2h_bits(r[5]) << 16);
            unsigned int w3 = (unsigned int)f2h_bits(r[6]) | ((unsigned int)f2h_bits(r[7]) << 16);
            uint4 q = { w0, w1, w2, w3 };
            *(uint4*)(void*)(o + (size_t)node * D + ch) = q;
        } else {
            float* o = (float*)outv;
            float4 w0 = { r[0], r[1], r[2], r[3] };
            float4 w1 = { r[4], r[5], r[6], r[7] };
            *(float4*)(o + (size_t)node * D + ch) = w0;
            *(float4*)(o + (size_t)node * D + ch + 4) = w1;
        }
    }
}

// ---------------------------------------------------------------------------
extern "C" void kernel_launch(void* const* d_in, const int* in_sizes, int n_in,
                              void* d_out, int out_size, void* d_ws, size_t ws_size,
                              hipStream_t stream)
{
    const float* x        = (const float*)d_in[0];
    const int*   eidx     = (const int*)  d_in[1];
    const float* W1       = (const float*)d_in[2];
    const float* att_src1 = (const float*)d_in[3];
    const float* att_dst1 = (const float*)d_in[4];
    const float* bias1    = (const float*)d_in[5];
    const float* W2       = (const float*)d_in[6];
    const float* att_src2 = (const float*)d_in[7];
    const float* att_dst2 = (const float*)d_in[8];
    const float* bias2    = (const float*)d_in[9];
    float* out = (float*)d_out;

    const int N_ = in_sizes[0] / 128;
    const int E_ = in_sizes[1] / 2;
    const int ET = E_ + N_;
    const int NB = (N_ + 255) / 256;

    char* p = (char*)d_ws;
    auto alloc = [&](size_t bytes) {
        void* r = (void*)p;
        p += ((bytes + 255) / 256) * 256;
        return r;
    };
    int* rowp  = (int*)alloc((size_t)(N_ + 1) * 4);
    int* cfill = (int*)alloc((size_t)NB_BUCKETS * 4);
    int* colidx = (int*)alloc((size_t)ET * 4);
    unsigned int*   tmp   = (unsigned int*)alloc((size_t)NB_BUCKETS * BCAP * 4);
    // h1f16 no longer aliases tmp: gemm1 runs concurrently with splitA (R6)
    unsigned short* h1f16 = (unsigned short*)alloc((size_t)N_ * 128 * 2);
    unsigned short* hx16  = (unsigned short*)alloc((size_t)N_ * 128 * 2);
    unsigned short* h2f16 = (unsigned short*)alloc((size_t)N_ * 64 * 2);
    float* as1 = (float*)alloc((size_t)N_ * 4 * 4);
    float* ad1 = (float*)alloc((size_t)N_ * 4 * 4);
    float* as2 = (float*)alloc((size_t)N_ * 4);
    float* ad2 = (float*)alloc((size_t)N_ * 4);
    (void)ws_size; (void)n_in; (void)out_size;

    const int nbh = (N_ + 3) / 4;            // node-blocks per half
    const int nbG = (N_ + 63) / 64;          // gemm1 blocks
    const int nbA = (ET + 4095) / 4096;      // splitA blocks

    // 1) zero bucket counters
    hipMemsetAsync(cfill, 0, (size_t)NB_BUCKETS * 4, stream);
    // 2) fat kernel: gemm_attn1 (MFMA) || splitA (LDS/mem) — independent
    build_and_gemm1_kernel<<<nbG + nbA, 256, 0, stream>>>(
        eidx, tmp, cfill, E_, ET, NB,
        x, W1, att_src1, att_dst1, h1f16, as1, ad1, N_, nbG);
    // 3) counting sort per bucket (inline scan) -> col + rowp
    passB_kernel<<<NB, 1024, 0, stream>>>(tmp, cfill, colidx, rowp, N_, NB, ET);
    // 4) layer-1 aggregate, channel-split halves in one dispatch
    aggregate_split<4, 32, true, true><<<2 * nbh, 256, 0, stream>>>(
        rowp, colidx, h1f16, as1, ad1, bias1, hx16, N_, nbh);
    // 5) layer-2 gemm+attn (reads fp16 hx)
    gemm_attn2_kernel<<<nbG, 256, 0, stream>>>(
        hx16, W2, att_src2, att_dst2, h2f16, as2, ad2, N_);
    // 6) layer-2 aggregate, channel-split halves, fp32 out
    aggregate_split<1, 64, false, false><<<2 * nbh, 256, 0, stream>>>(
        rowp, colidx, h2f16, as2, ad2, bias2, out, N_, nbh);
}

// Round 7
// 232.201 us; speedup vs baseline: 1.1685x; 1.1685x over previous
//
#include <hip/hip_runtime.h>
#include <hip/hip_fp16.h>
#include <math.h>

// ---------------------------------------------------------------------------
// GAT 2-layer forward. N=50000, E=1.6M (+N self loops), F: 128 -> (4x32) -> 64.
// R2: CSR via two-pass bucket sort of packed (dst<<16|src) codes.
// R4: fp16-MFMA GEMMs with fused attention-dot epilogue; fp16 inter-stage.
// R5: LDS (exp,offset) exchange in aggregates (full-channel; proven 61 us).
// R6-kept: splitA||gemm1 fat kernel; passB with inline scan (8->6 dispatches).
// R6-reverted: channel-split aggregation (6.4MB half still > 4MB L2; producer
// recompute + LDS conflicts made it VALU-bound: 61->83 us. Full-channel wins.)
// ---------------------------------------------------------------------------

#define NB_BUCKETS 256   // max coarse buckets (dst>>8); actual used = ceil(N/256)
#define BCAP 16384       // fixed capacity per coarse bucket region (avg ~8448)

typedef _Float16 half8 __attribute__((ext_vector_type(8)));
typedef float    floatx4 __attribute__((ext_vector_type(4)));

__device__ __forceinline__ unsigned short f2h_bits(float f) {
    return __half_as_ushort(__float2half(f));
}
__device__ __forceinline__ float h2f_lo(unsigned int u) {
    return __half2float(__ushort_as_half((unsigned short)(u & 0xFFFFu)));
}
__device__ __forceinline__ float h2f_hi(unsigned int u) {
    return __half2float(__ushort_as_half((unsigned short)(u >> 16)));
}

// ---------------------------------------------------------------------------
// splitA body: block-aggregated split into coarse buckets by dst>>8
// ---------------------------------------------------------------------------
__device__ void splitA_body(int bx, const int* __restrict__ eidx,
        unsigned int* __restrict__ tmp, int* __restrict__ coarse_fill,
        int E, int etot, int nb)
{
    __shared__ int hist[NB_BUCKETS];
    __shared__ int gb[NB_BUCKETS];
    __shared__ int cnt2[NB_BUCKETS];
    int t = threadIdx.x;
    if (t < nb) { hist[t] = 0; cnt2[t] = 0; }
    __syncthreads();

    unsigned int val[16];
    int bkt[16];
    int base = bx * 4096;
    #pragma unroll
    for (int i = 0; i < 16; i++) {
        int idx = base + i * 256 + t;
        if (idx < etot) {
            unsigned int s, d;
            if (idx < E) { s = (unsigned int)eidx[idx]; d = (unsigned int)eidx[E + idx]; }
            else         { s = (unsigned int)(idx - E); d = s; }
            val[i] = (d << 16) | s;
            bkt[i] = (int)(d >> 8);
            atomicAdd(&hist[bkt[i]], 1);
        } else {
            bkt[i] = -1;
        }
    }
    __syncthreads();
    if (t < nb) {
        int n = hist[t];
        gb[t] = (n > 0) ? atomicAdd(&coarse_fill[t], n) : 0;
    }
    __syncthreads();
    #pragma unroll
    for (int i = 0; i < 16; i++) {
        if (bkt[i] >= 0) {
            int loc = atomicAdd(&cnt2[bkt[i]], 1);
            tmp[(size_t)bkt[i] * BCAP + gb[bkt[i]] + loc] = val[i];
        }
    }
}

// ---------------------------------------------------------------------------
// GEMM (fp16 MFMA) + attention dots + fp16 payload emission (device body).
// ---------------------------------------------------------------------------
template<int NT, int H, bool AF16>
__device__ void gemm_attn_body(int bx,
        const void* __restrict__ Xv, const float* __restrict__ W,
        const float* __restrict__ att_s, const float* __restrict__ att_d,
        unsigned short* __restrict__ Hf16, float* __restrict__ as_,
        float* __restrict__ ad_, int M)
{
    constexpr int D = NT * 16;      // output width
    constexpr int C = D / H;        // channels per head
    __shared__ _Float16 Bs[NT * 4 * 64 * 8];

    int t = threadIdx.x;
    for (int idx = t; idx < 128 * D; idx += 256) {
        int k = idx / D;
        int n = idx - k * D;
        int nt = n >> 4, ks = k >> 5;
        int lane = (((k >> 3) & 3) << 4) | (n & 15);
        int j = k & 7;
        Bs[(((nt * 4 + ks) * 64 + lane) << 3) + j] = (_Float16)W[idx];
    }
    __syncthreads();

    int lane = t & 63;
    int wv = t >> 6;
    int quad = lane >> 4, colL = lane & 15;
    int row0 = bx * 64 + wv * 16;

    int arow = row0 + colL; if (arow > M - 1) arow = M - 1;
    half8 afrag[4];
    if constexpr (AF16) {
        const unsigned short* Xh = (const unsigned short*)Xv;
        #pragma unroll
        for (int ks = 0; ks < 4; ks++)
            afrag[ks] = *(const half8*)(const void*)(Xh + (size_t)arow * 128 + ks * 32 + quad * 8);
    } else {
        const float* Xf = (const float*)Xv;
        #pragma unroll
        for (int ks = 0; ks < 4; ks++) {
            const float* pa = Xf + (size_t)arow * 128 + ks * 32 + quad * 8;
            float4 a0 = *(const float4*)pa;
            float4 a1 = *(const float4*)(pa + 4);
            half8 f;
            f[0] = (_Float16)a0.x; f[1] = (_Float16)a0.y;
            f[2] = (_Float16)a0.z; f[3] = (_Float16)a0.w;
            f[4] = (_Float16)a1.x; f[5] = (_Float16)a1.y;
            f[6] = (_Float16)a1.z; f[7] = (_Float16)a1.w;
            afrag[ks] = f;
        }
    }

    floatx4 acc[NT];
    #pragma unroll
    for (int nt = 0; nt < NT; nt++) {
        floatx4 c = {0.f, 0.f, 0.f, 0.f};
        #pragma unroll
        for (int ks = 0; ks < 4; ks++) {
            half8 b = *(half8*)(void*)&Bs[(((nt * 4 + ks) * 64 + lane) << 3)];
            c = __builtin_amdgcn_mfma_f32_16x16x32_f16(afrag[ks], b, c, 0, 0, 0);
        }
        acc[nt] = c;
    }

    float atts[NT], attd[NT];
    #pragma unroll
    for (int nt = 0; nt < NT; nt++) {
        int ch = nt * 16 + colL;
        atts[nt] = att_s[ch];
        attd[nt] = att_d[ch];
    }
    float ps[H][4], pd[H][4];
    #pragma unroll
    for (int h = 0; h < H; h++)
        #pragma unroll
        for (int r = 0; r < 4; r++) { ps[h][r] = 0.f; pd[h][r] = 0.f; }
    #pragma unroll
    for (int nt = 0; nt < NT; nt++) {
        int h = (nt * 16) / C;
        #pragma unroll
        for (int r = 0; r < 4; r++) {
            ps[h][r] += acc[nt][r] * atts[nt];
            pd[h][r] += acc[nt][r] * attd[nt];
        }
    }
    #pragma unroll
    for (int h = 0; h < H; h++)
        #pragma unroll
        for (int r = 0; r < 4; r++)
            #pragma unroll
            for (int off = 1; off < 16; off <<= 1) {
                ps[h][r] += __shfl_xor(ps[h][r], off);
                pd[h][r] += __shfl_xor(pd[h][r], off);
            }
    if (colL < H) {
        #pragma unroll
        for (int r = 0; r < 4; r++) {
            int row = row0 + quad * 4 + r;
            if (row < M) {
                float vs, vd;
                if constexpr (H == 4) {
                    vs = colL == 0 ? ps[0][r] : colL == 1 ? ps[1][r] : colL == 2 ? ps[2][r] : ps[3][r];
                    vd = colL == 0 ? pd[0][r] : colL == 1 ? pd[1][r] : colL == 2 ? pd[2][r] : pd[3][r];
                } else {
                    vs = ps[0][r]; vd = pd[0][r];
                }
                as_[(size_t)row * H + colL] = vs;
                ad_[(size_t)row * H + colL] = vd;
            }
        }
    }

    #pragma unroll
    for (int r = 0; r < 4; r++) {
        int row = row0 + quad * 4 + r;
        if (row < M) {
            #pragma unroll
            for (int nt = 0; nt < NT; nt++)
                Hf16[(size_t)row * D + nt * 16 + colL] = f2h_bits(acc[nt][r]);
        }
    }
}

// ---------------------------------------------------------------------------
// Fat kernel: gemm_attn1 (blocks [0,nbG)) + splitA (blocks [nbG, nbG+nbA)).
// ---------------------------------------------------------------------------
__global__ __launch_bounds__(256) void build_and_gemm1_kernel(
        const int* __restrict__ eidx, unsigned int* __restrict__ tmp,
        int* __restrict__ cfill, int E, int etot, int nb,
        const float* __restrict__ x, const float* __restrict__ W1,
        const float* __restrict__ att_s, const float* __restrict__ att_d,
        unsigned short* __restrict__ h1f16, float* __restrict__ as1,
        float* __restrict__ ad1, int M, int nbG)
{
    if ((int)blockIdx.x < nbG)
        gemm_attn_body<8, 4, false>((int)blockIdx.x, x, W1, att_s, att_d,
                                    h1f16, as1, ad1, M);
    else
        splitA_body((int)blockIdx.x - nbG, eidx, tmp, cfill, E, etot, nb);
}

// standalone layer-2 gemm+attn
__global__ __launch_bounds__(256) void gemm_attn2_kernel(
        const void* __restrict__ Xv, const float* __restrict__ W,
        const float* __restrict__ att_s, const float* __restrict__ att_d,
        unsigned short* __restrict__ Hf16, float* __restrict__ as_,
        float* __restrict__ ad_, int M)
{
    gemm_attn_body<4, 1, true>((int)blockIdx.x, Xv, W, att_s, att_d, Hf16, as_, ad_, M);
}

// ---------------------------------------------------------------------------
// pass B with inline scan: per-bucket counting sort by dst&255 -> col + rowp.
// ---------------------------------------------------------------------------
__global__ __launch_bounds__(1024) void passB_kernel(const unsigned int* __restrict__ tmp,
        const int* __restrict__ cfill, int* __restrict__ col,
        int* __restrict__ rowp, int N_, int nb, int etot)
{
    __shared__ int sd[256];
    __shared__ int hist2[256];
    __shared__ int scn[256];
    __shared__ int off2[256];
    int b = blockIdx.x;
    int t = threadIdx.x;

    // inline exclusive scan of cfill[0..nb) (each block redoes it; tiny)
    if (t < 256) sd[t] = (t < nb) ? cfill[t] : 0;
    __syncthreads();
    for (int off = 1; off < 256; off <<= 1) {
        int y = 0;
        if (t < 256 && t >= off) y = sd[t - off];
        __syncthreads();
        if (t < 256) sd[t] += y;
        __syncthreads();
    }
    int base = sd[b] - cfill[b];     // exclusive prefix for this bucket
    int n = cfill[b];
    const unsigned int* seg = tmp + (size_t)b * BCAP;

    if (t < 256) hist2[t] = 0;
    __syncthreads();
    for (int i = t; i < n; i += 1024) {
        unsigned int v = seg[i];
        atomicAdd(&hist2[(v >> 16) & 255], 1);
    }
    __syncthreads();
    int myc = (t < 256) ? hist2[t] : 0;
    if (t < 256) scn[t] = myc;
    __syncthreads();
    for (int off = 1; off < 256; off <<= 1) {
        int y = 0;
        if (t < 256 && t >= off) y = scn[t - off];
        __syncthreads();
        if (t < 256) scn[t] += y;
        __syncthreads();
    }
    if (t < 256) {
        int excl = scn[t] - myc;
        off2[t] = excl;
        int node = b * 256 + t;
        if (node <= N_) rowp[node] = base + excl;
        if (node == N_) rowp[N_] = etot;
    }
    __syncthreads();
    for (int i = t; i < n; i += 1024) {
        unsigned int v = seg[i];
        int bin = (v >> 16) & 255;
        int loc = atomicAdd(&off2[bin], 1);
        col[base + loc] = (int)(v & 0xFFFFu);
    }
}

// ---------------------------------------------------------------------------
// Fused online-softmax segment aggregate, one wave per destination node.
// Full-channel (R5 form): per-chunk (exp, byte-offset) exchange through
// per-wave LDS; inner loop is 1 ds_read_b64 + uint4 gather + 8 fma per slot.
// ---------------------------------------------------------------------------
template<int H, int C, bool ELU_, bool OUTF16>
__global__ __launch_bounds__(256) void aggregate_fused(
        const int* __restrict__ row_ptr, const int* __restrict__ col_src,
        const unsigned short* __restrict__ payload, const float* __restrict__ asv,
        const float* __restrict__ adv, const float* __restrict__ bias,
        void* __restrict__ outv, int nnodes)
{
    constexpr int D = H * C;
    constexpr int CPL = 8;            // channels per lane (uint4 of halves)
    constexpr int LPE = D / CPL;      // lanes per edge: 16 (L1) or 8 (L2)
    constexpr int EPI = 64 / LPE;     // edges per inner iter: 4 or 8
    __shared__ float2 exs[4][H][65];
    int wave = threadIdx.x >> 6, lane = threadIdx.x & 63;
    int node = blockIdx.x * 4 + wave;
    if (node >= nnodes) return;
    int start = row_ptr[node];
    int deg   = row_ptr[node + 1] - start;   // >= 1 (self loop)
    int li  = lane & (LPE - 1);
    int sub = lane / LPE;
    int myh = (li * CPL) / C;
    int lane_off = li * 16;                  // byte offset within a row

    float adh[H];
    #pragma unroll
    for (int h = 0; h < H; h++) adh[h] = adv[(size_t)node * H + h];

    float m[H];
    #pragma unroll
    for (int h = 0; h < H; h++) m[h] = -3.0e38f;
    float acc[CPL];
    #pragma unroll
    for (int k = 0; k < CPL; k++) acc[k] = 0.f;
    float sacc = 0.f;
    const char* pb = (const char*)payload;

    for (int c0 = 0; c0 < deg; c0 += 64) {
        int cnt = deg - c0; if (cnt > 64) cnt = 64;
        int idx = c0 + lane;
        int svec = 0;
        float e[H];
        if (idx < deg) {
            svec = col_src[start + idx];
            if constexpr (H == 4) {
                float4 av = *(const float4*)(asv + (size_t)svec * 4);
                float t0 = av.x + adh[0], t1 = av.y + adh[1];
                float t2 = av.z + adh[2], t3 = av.w + adh[3];
                e[0] = fmaxf(t0, 0.2f * t0); e[1] = fmaxf(t1, 0.2f * t1);
                e[2] = fmaxf(t2, 0.2f * t2); e[3] = fmaxf(t3, 0.2f * t3);
            } else {
                float tt = asv[svec] + adh[0];
                e[0] = fmaxf(tt, 0.2f * tt);
            }
        } else {
            #pragma unroll
            for (int h = 0; h < H; h++) e[h] = -3.0e38f;
        }
        // chunk max per head -> running max update + rescale
        float nm[H];
        #pragma unroll
        for (int h = 0; h < H; h++) {
            float v = e[h];
            #pragma unroll
            for (int off = 32; off >= 1; off >>= 1)
                v = fmaxf(v, __shfl_xor(v, off));
            nm[h] = fmaxf(m[h], v);
        }
        float sc = __expf(m[myh] - nm[myh]);  // first chunk: 0
        sacc *= sc;
        #pragma unroll
        for (int k = 0; k < CPL; k++) acc[k] *= sc;
        #pragma unroll
        for (int h = 0; h < H; h++) m[h] = nm[h];

        // producer: write {exp, row byte-offset} per head into wave-local LDS
        unsigned int boff = (unsigned int)svec * (unsigned int)(D * 2);
        float boff_f = __uint_as_float(boff);
        #pragma unroll
        for (int h = 0; h < H; h++) {
            float ex = (idx < deg) ? __expf(e[h] - m[h]) : 0.f;
            exs[wave][h][lane] = make_float2(ex, boff_f);
        }

        // consumer: EPI edges per iteration, no cross-lane ops, no masking
        int iters = (cnt + EPI - 1) / EPI;
        #pragma unroll 2
        for (int it = 0; it < iters; it++) {
            int el = it * EPI + sub;
            float2 v = exs[wave][myh][el];
            float exj = v.x;
            unsigned int off = __float_as_uint(v.y);
            uint4 hv = *(const uint4*)(const void*)(pb + off + lane_off);
            sacc += exj;
            acc[0] = fmaf(h2f_lo(hv.x), exj, acc[0]);
            acc[1] = fmaf(h2f_hi(hv.x), exj, acc[1]);
            acc[2] = fmaf(h2f_lo(hv.y), exj, acc[2]);
            acc[3] = fmaf(h2f_hi(hv.y), exj, acc[3]);
            acc[4] = fmaf(h2f_lo(hv.z), exj, acc[4]);
            acc[5] = fmaf(h2f_hi(hv.z), exj, acc[5]);
            acc[6] = fmaf(h2f_lo(hv.w), exj, acc[6]);
            acc[7] = fmaf(h2f_hi(hv.w), exj, acc[7]);
        }
    }

    #pragma unroll
    for (int off = LPE; off < 64; off <<= 1) {
        sacc += __shfl_xor(sacc, off);
        #pragma unroll
        for (int k = 0; k < CPL; k++) acc[k] += __shfl_xor(acc[k], off);
    }
    if (sub == 0) {
        float inv = 1.f / (sacc + 1e-16f);
        int ch = li * CPL;
        float r[CPL];
        #pragma unroll
        for (int k = 0; k < CPL; k++) {
            r[k] = acc[k] * inv + bias[ch + k];
            if (ELU_) r[k] = r[k] > 0.f ? r[k] : (__expf(r[k]) - 1.f);
        }
        if constexpr (OUTF16) {
            unsigned short* o = (unsigned short*)outv;
            unsigned int w0 = (unsigned int)f2h_bits(r[0]) | ((unsigned int)f2h_bits(r[1]) << 16);
            unsigned int w1 = (unsigned int)f2h_bits(r[2]) | ((unsigned int)f2h_bits(r[3]) << 16);
            unsigned int w2 = (unsigned int)f2h_bits(r[4]) | ((unsigned int)f2h_bits(r[5]) << 16);
            unsigned int w3 = (unsigned int)f2h_bits(r[6]) | ((unsigned int)f2h_bits(r[7]) << 16);
            uint4 q = { w0, w1, w2, w3 };
            *(uint4*)(void*)(o + (size_t)node * D + ch) = q;
        } else {
            float* o = (float*)outv;
            float4 w0 = { r[0], r[1], r[2], r[3] };
            float4 w1 = { r[4], r[5], r[6], r[7] };
            *(float4*)(o + (size_t)node * D + ch) = w0;
            *(float4*)(o + (size_t)node * D + ch + 4) = w1;
        }
    }
}

// ---------------------------------------------------------------------------
extern "C" void kernel_launch(void* const* d_in, const int* in_sizes, int n_in,
                              void* d_out, int out_size, void* d_ws, size_t ws_size,
                              hipStream_t stream)
{
    const float* x        = (const float*)d_in[0];
    const int*   eidx     = (const int*)  d_in[1];
    const float* W1       = (const float*)d_in[2];
    const float* att_src1 = (const float*)d_in[3];
    const float* att_dst1 = (const float*)d_in[4];
    const float* bias1    = (const float*)d_in[5];
    const float* W2       = (const float*)d_in[6];
    const float* att_src2 = (const float*)d_in[7];
    const float* att_dst2 = (const float*)d_in[8];
    const float* bias2    = (const float*)d_in[9];
    float* out = (float*)d_out;

    const int N_ = in_sizes[0] / 128;
    const int E_ = in_sizes[1] / 2;
    const int ET = E_ + N_;
    const int NB = (N_ + 255) / 256;

    char* p = (char*)d_ws;
    auto alloc = [&](size_t bytes) {
        void* r = (void*)p;
        p += ((bytes + 255) / 256) * 256;
        return r;
    };
    int* rowp  = (int*)alloc((size_t)(N_ + 1) * 4);
    int* cfill = (int*)alloc((size_t)NB_BUCKETS * 4);
    int* colidx = (int*)alloc((size_t)ET * 4);
    unsigned int*   tmp   = (unsigned int*)alloc((size_t)NB_BUCKETS * BCAP * 4);
    // h1f16 must not alias tmp: gemm1 runs concurrently with splitA (R6)
    unsigned short* h1f16 = (unsigned short*)alloc((size_t)N_ * 128 * 2);
    unsigned short* hx16  = (unsigned short*)alloc((size_t)N_ * 128 * 2);
    unsigned short* h2f16 = (unsigned short*)alloc((size_t)N_ * 64 * 2);
    float* as1 = (float*)alloc((size_t)N_ * 4 * 4);
    float* ad1 = (float*)alloc((size_t)N_ * 4 * 4);
    float* as2 = (float*)alloc((size_t)N_ * 4);
    float* ad2 = (float*)alloc((size_t)N_ * 4);
    (void)ws_size; (void)n_in; (void)out_size;

    const int nbG = (N_ + 63) / 64;          // gemm1 blocks
    const int nbA = (ET + 4095) / 4096;      // splitA blocks

    // 1) zero bucket counters
    hipMemsetAsync(cfill, 0, (size_t)NB_BUCKETS * 4, stream);
    // 2) fat kernel: gemm_attn1 (MFMA) || splitA (LDS/mem) — independent
    build_and_gemm1_kernel<<<nbG + nbA, 256, 0, stream>>>(
        eidx, tmp, cfill, E_, ET, NB,
        x, W1, att_src1, att_dst1, h1f16, as1, ad1, N_, nbG);
    // 3) counting sort per bucket (inline scan) -> col + rowp
    passB_kernel<<<NB, 1024, 0, stream>>>(tmp, cfill, colidx, rowp, N_, NB, ET);
    // 4) layer-1 aggregate (full-channel, R5 form)
    aggregate_fused<4, 32, true, true><<<(N_ + 3) / 4, 256, 0, stream>>>(
        rowp, colidx, h1f16, as1, ad1, bias1, hx16, N_);
    // 5) layer-2 gemm+attn (reads fp16 hx)
    gemm_attn2_kernel<<<nbG, 256, 0, stream>>>(
        hx16, W2, att_src2, att_dst2, h2f16, as2, ad2, N_);
    // 6) layer-2 aggregate, fp32 out
    aggregate_fused<1, 64, false, false><<<(N_ + 3) / 4, 256, 0, stream>>>(
        rowp, colidx, h2f16, as2, ad2, bias2, out, N_);
}